// Round 13
// baseline (715.833 us; speedup 1.0000x reference)
//
#include <hip/hip_runtime.h>

#define T_LEN 2048
#define HID   25
#define LOG2E 1.4426950408889634f

// may_alias vectors for the LDS readbacks (rows are written as scalar float):
// without may_alias, TBAA licenses hoisting the reads above the publish
// (the R3/R7 corruption).
typedef float vf4 __attribute__((vector_size(16), may_alias));
typedef float vf2 __attribute__((vector_size(8),  may_alias));
typedef float f2  __attribute__((ext_vector_type(2)));

__device__ __forceinline__ float fast_rcp(float x) { return __builtin_amdgcn_rcpf(x); }
__device__ __forceinline__ float fast_exp2(float x) { return __builtin_amdgcn_exp2f(x); }

// R13: TWO time-interleaved chains per 64-lane wave, R9 gate layout per chain.
// Lane u (lower) owns rows i_u,g_u; lane 32+u (upper) owns f_u,o_u; one
// shfl_xor(32) hands i*tanh(g) to the upper half, which owns c,h (R9 math,
// passed at 1.953e-3). Both chains share the SAME weight registers (w_hh is
// chain-independent): 26 f2 pairs x 2 gates = 52 VGPRs total.
// WHY two chains: R11's wall was 639 cyc/step = 426 issue + ~213 exposed
// serial latency (LDS round trip + trans chain) at 1 wave/SIMD; waves issue
// IN ORDER, so only independent work in the same wave can fill those stalls.
// Chain B's dot/trans is exactly that filler. 2048/2 = 1024 waves = still
// 1 wave/SIMD. No fences: publish->readback order is enforced by may_alias
// on the same row; A-row vs B-row are provably disjoint, so the scheduler
// may interleave the chains freely.
// Per-gate pk pairing identical to R11: acc.x = k=0..11 (+h24*w24),
// acc.y = k=12..23, horizontal add last.
// h rows are stored interleaved [h0,h12,h1,h13,...,h11,h23,h24,0,...] in a
// 36-float row (144 B, b128-aligned) per (chain, t mod 32); the same rows
// double as the y-batch history (read every 32 steps, 13 vf2 + pk).

__global__ __attribute__((amdgpu_flat_work_group_size(256, 256),
                          amdgpu_waves_per_eu(1, 1)))
void lstm_fused(
    const float* __restrict__ x,        // [B, T, 1]
    const float* __restrict__ w_ih,     // [100, 1]
    const float* __restrict__ w_hh,     // [100, 25]
    const float* __restrict__ b_ih,     // [100]
    const float* __restrict__ b_hh,     // [100]
    const float* __restrict__ w_dense,  // [1, 25]
    const float* __restrict__ b_dense,  // [1]
    float* __restrict__ out)            // [B, T, 1]
{
    const int tid  = threadIdx.x;
    const int L    = tid & 63;           // lane in wave
    const int u    = L & 31;             // hidden unit / y-slot for this lane
    const bool up  = L >= 32;            // upper half: f/o rows, owns c and h
    const int cl   = tid >> 6;           // wave index in block, 0..3
    const int bA   = blockIdx.x * 8 + 2 * cl;      // chain A
    const int bB   = bA + 1;                       // chain B
    const bool act = u < HID;

    // hist[2 chains per wave x 4 waves][32 steps][36 floats interleaved]
    __shared__ __align__(16) float hist[8][32][36];

    // per-wave zero init (slots >=25 must read as 0 forever; same-wave DS
    // ordering + may_alias keeps this before the first readback)
    {
        float* myh = &hist[2 * cl][0][0];
        for (int i = L; i < 2 * 32 * 36; i += 64) myh[i] = 0.f;
    }

    const int rowAg = up ? (HID + u)     : u;              // f-row : i-row
    const int rowBg = up ? (3 * HID + u) : (2 * HID + u);  // o-row : g-row
    const float sclA = -LOG2E;                             // sigmoid gates
    const float sclB = up ? -LOG2E : 2.f * LOG2E;          // o: sig, g: tanh

    // ---- shared recurrent weights as (k, k+12) pairs + (w24, 0) ----
    f2 wA2[13], wB2[13];
#pragma unroll
    for (int m = 0; m < 12; ++m) {
        wA2[m] = act ? f2{sclA * w_hh[rowAg * HID + m], sclA * w_hh[rowAg * HID + m + 12]} : f2{0.f, 0.f};
        wB2[m] = act ? f2{sclB * w_hh[rowBg * HID + m], sclB * w_hh[rowBg * HID + m + 12]} : f2{0.f, 0.f};
    }
    wA2[12] = act ? f2{sclA * w_hh[rowAg * HID + 24], 0.f} : f2{0.f, 0.f};
    wB2[12] = act ? f2{sclB * w_hh[rowBg * HID + 24], 0.f} : f2{0.f, 0.f};

    const float bAc = act ? sclA * (b_ih[rowAg] + b_hh[rowAg]) : 0.f;
    const float bBc = act ? sclB * (b_ih[rowBg] + b_hh[rowBg]) : 0.f;
    const float wxA = act ? sclA * w_ih[rowAg] : 0.f;
    const float wxB = act ? sclB * w_ih[rowBg] : 0.f;
    const float bd  = b_dense[0];
    // tB = fmaf(-tmul, sB, 1): tanh(g) on lower half, exactly 1.0 on upper
    const float tmul = up ? 0.f : 2.f;

    // dense weights paired to match the interleaved rows (wave-uniform)
    f2 wd2[13];
#pragma unroll
    for (int m = 0; m < 12; ++m) wd2[m] = f2{w_dense[m], w_dense[m + 12]};
    wd2[12] = f2{w_dense[24], 0.f};

    // interleaved publish slot (bijection over u=0..24)
    const int slot = (u < 12) ? 2 * u : (u < 24) ? 2 * u - 23 : 24;

    const float4* __restrict__ xpA = (const float4*)(x + (size_t)bA * T_LEN);
    const float4* __restrict__ xpB = (const float4*)(x + (size_t)bB * T_LEN);
    float* __restrict__ orowA = out + (size_t)bA * T_LEN;
    float* __restrict__ orowB = out + (size_t)bB * T_LEN;
    // y store target: lower half stores chain A, upper half chain B
    float* __restrict__ yout = up ? orowB : orowA;
    // y history row for this lane (fixed): chain (2cl + up), step-slot u
    const float* myrow = &hist[2 * cl + (up ? 1 : 0)][u][0];

    // per-chain h state (13 aligned pairs) and cell state
    f2 hpA[13], hpB[13];
#pragma unroll
    for (int m = 0; m < 13; ++m) { hpA[m] = f2{0.f, 0.f}; hpB[m] = f2{0.f, 0.f}; }
    float cA = 0.f, cB = 0.f;

    float4 xcurA = xpA[0];
    float4 xcurB = xpB[0];

    for (int it = 0; it < T_LEN / 4; ++it) {
        const int nx = (it + 1 < T_LEN / 4) ? it + 1 : it;
        float4 xnextA = xpA[nx];  // prefetch ~4 steps ahead
        float4 xnextB = xpB[nx];
        float xsA[4] = {xcurA.x, xcurA.y, xcurA.z, xcurA.w};
        float xsB[4] = {xcurB.x, xcurB.y, xcurB.z, xcurB.w};

#pragma unroll
        for (int s = 0; s < 4; ++s) {
            const int t = 4 * it + s;
            float* rowA = &hist[2 * cl][t & 31][0];
            float* rowB = &hist[2 * cl + 1][t & 31][0];

            // ---- chain A: gates (26 pk), trans, c/h update ----
            f2 aAv = f2{fmaf(xsA[s], wxA, bAc), 0.f};
            f2 aBv = f2{fmaf(xsA[s], wxB, bBc), 0.f};
#pragma unroll
            for (int m = 0; m < 13; ++m) {
                const f2 h = hpA[m];
                aAv = __builtin_elementwise_fma(h, wA2[m], aAv);
                aBv = __builtin_elementwise_fma(h, wB2[m], aBv);
            }
            const float aA_A = aAv.x + aAv.y;
            const float aB_A = aBv.x + aBv.y;
            const float sA_A = fast_rcp(1.f + fast_exp2(aA_A));  // sig(i)/sig(f)
            const float sB_A = fast_rcp(1.f + fast_exp2(aB_A));  // g-aux/sig(o)
            const float tB_A = fmaf(-tmul, sB_A, 1.f);           // tanh(g)/1
            const float vvA  = sA_A * tB_A;
            const float ovA  = __shfl_xor(vvA, 32, 64);
            cA = fmaf(vvA, cA, ovA);
            const float tC_A = fmaf(-2.f, fast_rcp(1.f + fast_exp2(2.f * LOG2E * cA)), 1.f);
            const float hnA  = sB_A * tC_A;      // upper: o*tanh(c)

            // ---- chain B: identical, independent (scheduler filler) ----
            f2 aAv2 = f2{fmaf(xsB[s], wxA, bAc), 0.f};
            f2 aBv2 = f2{fmaf(xsB[s], wxB, bBc), 0.f};
#pragma unroll
            for (int m = 0; m < 13; ++m) {
                const f2 h = hpB[m];
                aAv2 = __builtin_elementwise_fma(h, wA2[m], aAv2);
                aBv2 = __builtin_elementwise_fma(h, wB2[m], aBv2);
            }
            const float aA_B = aAv2.x + aAv2.y;
            const float aB_B = aBv2.x + aBv2.y;
            const float sA_B = fast_rcp(1.f + fast_exp2(aA_B));
            const float sB_B = fast_rcp(1.f + fast_exp2(aB_B));
            const float tB_B = fmaf(-tmul, sB_B, 1.f);
            const float vvB  = sA_B * tB_B;
            const float ovB  = __shfl_xor(vvB, 32, 64);
            cB = fmaf(vvB, cB, ovB);
            const float tC_B = fmaf(-2.f, fast_rcp(1.f + fast_exp2(2.f * LOG2E * cB)), 1.f);
            const float hnB  = sB_B * tC_B;

            // ---- publish both (upper real lanes only; one exec mask) ----
            if (up && act) { rowA[slot] = hnA; rowB[slot] = hnB; }

            // ---- readback both (may_alias orders vs the publishes) ----
            {
                vf4 a0 = ((const vf4*)rowA)[0], a1 = ((const vf4*)rowA)[1];
                vf4 a2 = ((const vf4*)rowA)[2], a3 = ((const vf4*)rowA)[3];
                vf4 a4 = ((const vf4*)rowA)[4], a5 = ((const vf4*)rowA)[5];
                vf2 a6 = *(const vf2*)(rowA + 24);
                hpA[0]  = f2{a0[0], a0[1]}; hpA[1]  = f2{a0[2], a0[3]};
                hpA[2]  = f2{a1[0], a1[1]}; hpA[3]  = f2{a1[2], a1[3]};
                hpA[4]  = f2{a2[0], a2[1]}; hpA[5]  = f2{a2[2], a2[3]};
                hpA[6]  = f2{a3[0], a3[1]}; hpA[7]  = f2{a3[2], a3[3]};
                hpA[8]  = f2{a4[0], a4[1]}; hpA[9]  = f2{a4[2], a4[3]};
                hpA[10] = f2{a5[0], a5[1]}; hpA[11] = f2{a5[2], a5[3]};
                hpA[12] = f2{a6[0], a6[1]};
            }
            {
                vf4 a0 = ((const vf4*)rowB)[0], a1 = ((const vf4*)rowB)[1];
                vf4 a2 = ((const vf4*)rowB)[2], a3 = ((const vf4*)rowB)[3];
                vf4 a4 = ((const vf4*)rowB)[4], a5 = ((const vf4*)rowB)[5];
                vf2 a6 = *(const vf2*)(rowB + 24);
                hpB[0]  = f2{a0[0], a0[1]}; hpB[1]  = f2{a0[2], a0[3]};
                hpB[2]  = f2{a1[0], a1[1]}; hpB[3]  = f2{a1[2], a1[3]};
                hpB[4]  = f2{a2[0], a2[1]}; hpB[5]  = f2{a2[2], a2[3]};
                hpB[6]  = f2{a3[0], a3[1]}; hpB[7]  = f2{a3[2], a3[3]};
                hpB[8]  = f2{a4[0], a4[1]}; hpB[9]  = f2{a4[2], a4[3]};
                hpB[10] = f2{a5[0], a5[1]}; hpB[11] = f2{a5[2], a5[3]};
                hpB[12] = f2{a6[0], a6[1]};
            }

            // ---- batched y: every 32 steps, lane reads its own hist row
            // (step t0+u of its chain) and stores one coalesced value ----
            if ((t & 31) == 31) {
                f2 accY = f2{0.f, 0.f};
#pragma unroll
                for (int m = 0; m < 13; ++m) {
                    vf2 hm = ((const vf2*)myrow)[m];
                    accY = __builtin_elementwise_fma(f2{hm[0], hm[1]}, wd2[m], accY);
                }
                yout[(t & ~31) + u] = accY.x + accY.y + bd;  // 128 B per half
            }
        }
        xcurA = xnextA;
        xcurB = xnextB;
    }
}

extern "C" void kernel_launch(void* const* d_in, const int* in_sizes, int n_in,
                              void* d_out, int out_size, void* d_ws, size_t ws_size,
                              hipStream_t stream) {
    const float* x       = (const float*)d_in[0];
    const float* w_ih    = (const float*)d_in[1];
    const float* w_hh    = (const float*)d_in[2];
    const float* b_ih    = (const float*)d_in[3];
    const float* b_hh    = (const float*)d_in[4];
    const float* w_dense = (const float*)d_in[5];
    const float* b_dense = (const float*)d_in[6];
    float* out = (float*)d_out;

    // 2048 chains, TWO per 64-lane wave: 256 blocks x 256 threads
    // -> 1024 waves = 1 wave/SIMD chip-wide, 4 waves/CU.
    lstm_fused<<<dim3(256), dim3(256), 0, stream>>>(x, w_ih, w_hh, b_ih, b_hh,
                                                    w_dense, b_dense, out);
}

// Round 14
// 580.729 us; speedup vs baseline: 1.2326x; 1.2326x over previous
//
#include <hip/hip_runtime.h>

#define T_LEN 2048
#define HID   25
#define LOG2E 1.4426950408889634f

// may_alias vectors for the LDS readbacks (rows are written as scalar float):
// without may_alias, TBAA licenses hoisting the reads above the publish
// (the R3/R7 corruption).
typedef float vf4 __attribute__((vector_size(16), may_alias));
typedef float vf2 __attribute__((vector_size(8),  may_alias));
typedef float f2  __attribute__((ext_vector_type(2)));

__device__ __forceinline__ float fast_rcp(float x) { return __builtin_amdgcn_rcpf(x); }
__device__ __forceinline__ float fast_exp2(float x) { return __builtin_amdgcn_exp2f(x); }

// R14 = R11 (545 us champion) de-crufted.
// One chain per 32-lane half-wave; lane u owns ALL FOUR gate rows of unit u.
// 1024 waves = 1 wave/SIMD; waves_per_eu(1,1) -> full VGPR budget (R8 lesson).
// Changes vs R11 (all issue-count cuts; structure identical):
//  * t-loop unrolled x32: every (t&31) is compile-time -> no yroll cndmask,
//    no per-step branch, no xs select, and ALL hist addressing becomes
//    immediate DS offsets (zero per-step address arithmetic).
//  * single interleaved hist array replaces hbuf+hist (R13 trick): ONE
//    ds_write per step, unconditional (junk lanes u>=25 write slot u+1,
//    outside the 0..25 read window) -> no exec-mask dance.
//  * c kept in exp2 domain (C = 2log2e*c): the scale folds into tanh(g)'s
//    fmaf constants (tGs = 2log2e - 4log2e*rG), removing a mul from the
//    serial c->tanh(c) critical path.
//  * x double-buffered 32 steps ahead (8 float4 loads per 32 steps).
// DS per wave-step ~= 8.4 ops (~100 cyc/CU at 4 waves/CU -- far under the
// ~770-cyc DS-pipe wall that bound R13/R9/R5).
// KEPT: interleaved (k,k+12) pk pairing bit-identical to R11 (floor 1.953e-3);
// v_pk_fma_f32 saves no throughput on gfx950 (fp32 peak = scalar rate) but
// halves instruction COUNT, which cuts decode/schedule overhead.
// Row pair 12 = (h24, slot25) x (w24, 0): slot 25 is zero-initialized once
// (NaN*0=NaN, so it must be finite); its value is otherwise irrelevant.

__global__ __attribute__((amdgpu_flat_work_group_size(256, 256),
                          amdgpu_waves_per_eu(1, 1)))
void lstm_fused(
    const float* __restrict__ x,        // [B, T, 1]
    const float* __restrict__ w_ih,     // [100, 1]
    const float* __restrict__ w_hh,     // [100, 25]
    const float* __restrict__ b_ih,     // [100]
    const float* __restrict__ b_hh,     // [100]
    const float* __restrict__ w_dense,  // [1, 25]
    const float* __restrict__ b_dense,  // [1]
    float* __restrict__ out)            // [B, T, 1]
{
    const int tid  = threadIdx.x;
    const int u    = tid & 31;           // hidden unit / y-slot owned by lane
    const int cb   = tid >> 5;           // chain index in block, 0..7
    const int b    = blockIdx.x * 8 + cb;
    const bool act = u < HID;

    // hist[chain][step mod 32][36]: interleaved h rows
    // [h0,h12,h1,h13,...,h11,h23,h24,Z,junk...] (Z = permanent zero, slot 25).
    // Row stride 144 B (16B-aligned). Doubles as the y-batch history.
    __shared__ __align__(16) float hist[8][32][36];

    const float si = -LOG2E, sg = 2.f * LOG2E;

    // ---- recurrent weights as (k, k+12) pairs + (w24, 0), exp2 domain ----
    f2 wI2[13], wF2[13], wG2[13], wO2[13];
#pragma unroll
    for (int m = 0; m < 12; ++m) {
        wI2[m] = act ? f2{si * w_hh[u * HID + m],             si * w_hh[u * HID + m + 12]}             : f2{0.f, 0.f};
        wF2[m] = act ? f2{si * w_hh[(HID + u) * HID + m],     si * w_hh[(HID + u) * HID + m + 12]}     : f2{0.f, 0.f};
        wG2[m] = act ? f2{sg * w_hh[(2 * HID + u) * HID + m], sg * w_hh[(2 * HID + u) * HID + m + 12]} : f2{0.f, 0.f};
        wO2[m] = act ? f2{si * w_hh[(3 * HID + u) * HID + m], si * w_hh[(3 * HID + u) * HID + m + 12]} : f2{0.f, 0.f};
    }
    wI2[12] = act ? f2{si * w_hh[u * HID + 24], 0.f}             : f2{0.f, 0.f};
    wF2[12] = act ? f2{si * w_hh[(HID + u) * HID + 24], 0.f}     : f2{0.f, 0.f};
    wG2[12] = act ? f2{sg * w_hh[(2 * HID + u) * HID + 24], 0.f} : f2{0.f, 0.f};
    wO2[12] = act ? f2{si * w_hh[(3 * HID + u) * HID + 24], 0.f} : f2{0.f, 0.f};

    const float bI  = act ? si * (b_ih[u] + b_hh[u]) : 0.f;
    const float bF  = act ? si * (b_ih[HID + u] + b_hh[HID + u]) : 0.f;
    const float bG  = act ? sg * (b_ih[2 * HID + u] + b_hh[2 * HID + u]) : 0.f;
    const float bO  = act ? si * (b_ih[3 * HID + u] + b_hh[3 * HID + u]) : 0.f;
    const float wxI = act ? si * w_ih[u] : 0.f;
    const float wxF = act ? si * w_ih[HID + u] : 0.f;
    const float wxG = act ? sg * w_ih[2 * HID + u] : 0.f;
    const float wxO = act ? si * w_ih[3 * HID + u] : 0.f;
    const float bd  = b_dense[0];

    // dense weights paired to match the interleaved rows (wave-uniform)
    f2 wd2[13];
#pragma unroll
    for (int m = 0; m < 12; ++m) wd2[m] = f2{w_dense[m], w_dense[m + 12]};
    wd2[12] = f2{w_dense[24], 0.f};

    // zero slot 25 of every row once (lane u zeroes row u): it pairs with h24
    // in the b64 read and multiplies by 0 -- must be finite.
    hist[cb][u][25] = 0.f;

    // publish slot: bijection over real lanes; junk lanes park at u+1 (26..32),
    // outside the 0..25 read window. Unconditional ds_write, no exec mask.
    const int slot = act ? ((u < 12) ? 2 * u : (u < 24) ? 2 * u - 23 : 24)
                         : (u + 1);
    float* pw = &hist[cb][0][slot];       // per-lane write base (+144*j imm)
    const float* pr = &hist[cb][0][0];    // uniform read base   (+144*j imm)
    const float* py = &hist[cb][u][0];    // per-lane y row base

    const float4* __restrict__ xp = (const float4*)(x + (size_t)b * T_LEN);
    float* __restrict__ orow = out + (size_t)b * T_LEN;

    // h state as 13 register-aligned pairs (h_m, h_{m+12}), hp[12]=(h24,Z)
    f2 hp[13];
#pragma unroll
    for (int m = 0; m < 13; ++m) hp[m] = f2{0.f, 0.f};

    float C = 0.f;   // cell state, pre-scaled: C = 2*log2e*c

    float4 xc[8];
#pragma unroll
    for (int i = 0; i < 8; ++i) xc[i] = xp[i];

    for (int blk = 0; blk < 64; ++blk) {
        const int nb = (blk < 63) ? blk + 1 : blk;
        float4 xn[8];
#pragma unroll
        for (int i = 0; i < 8; ++i) xn[i] = xp[nb * 8 + i];  // ~32 steps ahead

#pragma unroll
        for (int j = 0; j < 32; ++j) {
            const float4 xq = xc[j >> 2];
            const float xv = ((j & 3) == 0) ? xq.x : ((j & 3) == 1) ? xq.y
                           : ((j & 3) == 2) ? xq.z : xq.w;

            // four gate pre-activations via pk-fma (13 pairs each);
            // pairing bit-identical to R11.
            f2 accI = f2{fmaf(xv, wxI, bI), 0.f};
            f2 accF = f2{fmaf(xv, wxF, bF), 0.f};
            f2 accG = f2{fmaf(xv, wxG, bG), 0.f};
            f2 accO = f2{fmaf(xv, wxO, bO), 0.f};
#pragma unroll
            for (int m = 0; m < 13; ++m) {
                const f2 h = hp[m];
                accI = __builtin_elementwise_fma(h, wI2[m], accI);
                accF = __builtin_elementwise_fma(h, wF2[m], accF);
                accG = __builtin_elementwise_fma(h, wG2[m], accG);
                accO = __builtin_elementwise_fma(h, wO2[m], accO);
            }
            const float aI = accI.x + accI.y;
            const float aF = accF.x + accF.y;
            const float aG = accG.x + accG.y;
            const float aO = accO.x + accO.y;

            const float sI = fast_rcp(1.f + fast_exp2(aI));   // sig(i)
            const float sF = fast_rcp(1.f + fast_exp2(aF));   // sig(f)
            const float sO = fast_rcp(1.f + fast_exp2(aO));   // sig(o)
            const float rG = fast_rcp(1.f + fast_exp2(aG));
            // tanh(g) pre-scaled by 2log2e: tGs = 2log2e - 4log2e*rG
            const float tGs = fmaf(-4.f * LOG2E, rG, 2.f * LOG2E);

            C = fmaf(sF, C, sI * tGs);                        // C = 2log2e*c
            const float tC = fmaf(-2.f, fast_rcp(1.f + fast_exp2(C)), 1.f);
            const float hn = sO * tC;

            // ---- ordered publish -> readback (immediate DS offsets) ----
            pw[36 * j] = hn;
            __asm__ __volatile__("" ::: "memory");
            {
                const vf4* r4 = (const vf4*)(pr + 36 * j);
                vf4 a0 = r4[0], a1 = r4[1], a2 = r4[2];
                vf4 a3 = r4[3], a4 = r4[4], a5 = r4[5];
                vf2 a6 = *(const vf2*)(pr + 36 * j + 24);     // (h24, Z)
                hp[0]  = f2{a0[0], a0[1]}; hp[1]  = f2{a0[2], a0[3]};
                hp[2]  = f2{a1[0], a1[1]}; hp[3]  = f2{a1[2], a1[3]};
                hp[4]  = f2{a2[0], a2[1]}; hp[5]  = f2{a2[2], a2[3]};
                hp[6]  = f2{a3[0], a3[1]}; hp[7]  = f2{a3[2], a3[3]};
                hp[8]  = f2{a4[0], a4[1]}; hp[9]  = f2{a4[2], a4[3]};
                hp[10] = f2{a5[0], a5[1]}; hp[11] = f2{a5[2], a5[3]};
                hp[12] = f2{a6[0], a6[1]};
            }

            // batched y at the unroll boundary (compile-time, no branch in
            // the other 31 steps): lane u reduces its own row (step t0+u).
            if (j == 31) {
                f2 accY = f2{0.f, 0.f};
#pragma unroll
                for (int m = 0; m < 13; ++m) {
                    vf2 hm = ((const vf2*)py)[m];
                    accY = __builtin_elementwise_fma(f2{hm[0], hm[1]}, wd2[m], accY);
                }
                orow[blk * 32 + u] = accY.x + accY.y + bd;    // 128 B coalesced
            }
        }

#pragma unroll
        for (int i = 0; i < 8; ++i) xc[i] = xn[i];
    }
}

extern "C" void kernel_launch(void* const* d_in, const int* in_sizes, int n_in,
                              void* d_out, int out_size, void* d_ws, size_t ws_size,
                              hipStream_t stream) {
    const float* x       = (const float*)d_in[0];
    const float* w_ih    = (const float*)d_in[1];
    const float* w_hh    = (const float*)d_in[2];
    const float* b_ih    = (const float*)d_in[3];
    const float* b_hh    = (const float*)d_in[4];
    const float* w_dense = (const float*)d_in[5];
    const float* b_dense = (const float*)d_in[6];
    float* out = (float*)d_out;

    // 2048 chains, one per 32-lane half-wave: 256 blocks x 256 threads
    // -> 1024 waves = 1 wave/SIMD chip-wide, 4 waves/CU.
    lstm_fused<<<dim3(256), dim3(256), 0, stream>>>(x, w_ih, w_hh, b_ih, b_hh,
                                                    w_dense, b_dense, out);
}

// Round 15
// 549.215 us; speedup vs baseline: 1.3034x; 1.0574x over previous
//
#include <hip/hip_runtime.h>

#define T_LEN 2048
#define HID   25
#define LOG2E 1.4426950408889634f

// may_alias vectors for the LDS h-row readback (written as scalar float):
// without may_alias, TBAA licenses hoisting the reads above the publish
// (the R3/R7 corruption).
typedef float vf4 __attribute__((vector_size(16), may_alias));
typedef float vf2 __attribute__((vector_size(8),  may_alias));
typedef float f4  __attribute__((ext_vector_type(4)));
typedef float f2  __attribute__((ext_vector_type(2)));

__device__ __forceinline__ float fast_rcp(float x) { return __builtin_amdgcn_rcpf(x); }
__device__ __forceinline__ float fast_exp2(float x) { return __builtin_amdgcn_exp2f(x); }

// R15 = R11 (545 us champion) + ONE change: the h readback stays in the
// loaded quads (six f4 + one f2) and the dot loop consumes aligned f2
// halves in place via shufflevector -- v_pk_fma_f32 reads any even-aligned
// VGPR pair, and a ds_read_b128 destination's [0:1]/[2:3] halves are
// exactly that. R11 repacked into 13 separate f2 (worst case ~26 v_mov
// per step ~= 52 issue cyc of the ~100-cyc gap between R11's measured 426
// issue cyc/step and the ~318 floor).
// Everything else is byte-identical to R11: one chain per 32-lane
// half-wave (lane u owns all 4 gate rows of unit u), 1024 waves =
// 1 wave/SIMD, waves_per_eu(1,1) (full VGPR budget, no AGPR demotion),
// interleaved hbuf broadcast row [h0,h12,h1,h13,...,h11,h23,h24,0,...]
// (slot bijection, junk lanes -> dump rows, ZERO bank conflicts --
// R14's stride-36 merge put 4-way conflicts inside the critical LDS
// round trip and regressed), separate stride-33 hist for the batched y,
// single compile-time fence between publish and readback.
// sigmoid/tanh in exp2 domain (weights pre-scaled by -log2e / +2log2e);
// (k, k+12) pk pairing -> summation order bit-identical to R5..R14
// (absmax exactly 1.953125e-3 = harness bf16 comparison floor).

__global__ __attribute__((amdgpu_flat_work_group_size(256, 256),
                          amdgpu_waves_per_eu(1, 1)))
void lstm_fused(
    const float* __restrict__ x,        // [B, T, 1]
    const float* __restrict__ w_ih,     // [100, 1]
    const float* __restrict__ w_hh,     // [100, 25]
    const float* __restrict__ b_ih,     // [100]
    const float* __restrict__ b_hh,     // [100]
    const float* __restrict__ w_dense,  // [1, 25]
    const float* __restrict__ b_dense,  // [1]
    float* __restrict__ out)            // [B, T, 1]
{
    const int tid  = threadIdx.x;
    const int u    = tid & 31;           // hidden unit / y-slot owned by lane
    const int cb   = tid >> 5;           // chain index in block, 0..7
    const int b    = blockIdx.x * 8 + cb;
    const bool act = u < HID;

    // rows 0..7: interleaved h rows per chain; rows 8..15: junk-lane dump.
    __shared__ __align__(16) float hbuf[16][32];
    // y history: 32 steps x 33 floats (stride 33 -> the lane=u strided read
    // in the y phase is conflict-free).
    __shared__ float hist[8][32][33];

    const float si = -LOG2E, sg = 2.f * LOG2E;

    // ---- recurrent weights as (k, k+12) pairs + (w24, 0), exp2 domain ----
    f2 wI2[13], wF2[13], wG2[13], wO2[13];
#pragma unroll
    for (int m = 0; m < 12; ++m) {
        wI2[m] = act ? f2{si * w_hh[u * HID + m],             si * w_hh[u * HID + m + 12]}             : f2{0.f, 0.f};
        wF2[m] = act ? f2{si * w_hh[(HID + u) * HID + m],     si * w_hh[(HID + u) * HID + m + 12]}     : f2{0.f, 0.f};
        wG2[m] = act ? f2{sg * w_hh[(2 * HID + u) * HID + m], sg * w_hh[(2 * HID + u) * HID + m + 12]} : f2{0.f, 0.f};
        wO2[m] = act ? f2{si * w_hh[(3 * HID + u) * HID + m], si * w_hh[(3 * HID + u) * HID + m + 12]} : f2{0.f, 0.f};
    }
    wI2[12] = act ? f2{si * w_hh[u * HID + 24], 0.f}             : f2{0.f, 0.f};
    wF2[12] = act ? f2{si * w_hh[(HID + u) * HID + 24], 0.f}     : f2{0.f, 0.f};
    wG2[12] = act ? f2{sg * w_hh[(2 * HID + u) * HID + 24], 0.f} : f2{0.f, 0.f};
    wO2[12] = act ? f2{si * w_hh[(3 * HID + u) * HID + 24], 0.f} : f2{0.f, 0.f};

    const float bI  = act ? si * (b_ih[u] + b_hh[u]) : 0.f;
    const float bF  = act ? si * (b_ih[HID + u] + b_hh[HID + u]) : 0.f;
    const float bG  = act ? sg * (b_ih[2 * HID + u] + b_hh[2 * HID + u]) : 0.f;
    const float bO  = act ? si * (b_ih[3 * HID + u] + b_hh[3 * HID + u]) : 0.f;
    const float wxI = act ? si * w_ih[u] : 0.f;
    const float wxF = act ? si * w_ih[HID + u] : 0.f;
    const float wxG = act ? sg * w_ih[2 * HID + u] : 0.f;
    const float wxO = act ? si * w_ih[3 * HID + u] : 0.f;
    const float bd  = b_dense[0];

    // dense weights (wave-uniform loads -> SGPRs)
    float wdv[HID];
#pragma unroll
    for (int i = 0; i < HID; ++i) wdv[i] = w_dense[i];

    // h0 = 0 everywhere (incl. the permanently-zero slot 25 and dump rows)
    hbuf[cb][u] = 0.f;
    hbuf[8 + cb][u] = 0.f;

    // interleaved publish slot (bijection 0..24); junk lanes -> dump row.
    // Pointer is loop-invariant: unconditional ds_write, no exec-mask dance.
    const int slot = (u < 12) ? 2 * u : (u < 24) ? 2 * u - 23 : 24;
    float* hwr = act ? &hbuf[cb][slot] : &hbuf[8 + cb][u];
    const vf4* r4 = (const vf4*)&hbuf[cb][0];
    const vf2* r2 = (const vf2*)&hbuf[cb][24];   // (h24, 0)

    const float4* __restrict__ xp = (const float4*)(x + (size_t)b * T_LEN);
    float* __restrict__ orow = out + (size_t)b * T_LEN;

    // h state kept in the loaded quads; pairs consumed in place.
    f4 hq[6];
#pragma unroll
    for (int m = 0; m < 6; ++m) hq[m] = f4{0.f, 0.f, 0.f, 0.f};
    f2 hq6 = f2{0.f, 0.f};

    float c = 0.f;
    float4 xcur = xp[0];

    for (int it = 0; it < T_LEN / 4; ++it) {
        const int nx = (it + 1 < T_LEN / 4) ? it + 1 : it;
        float4 xnext = xp[nx];  // issued ~4 steps ahead of use
        float xs[4] = {xcur.x, xcur.y, xcur.z, xcur.w};

#pragma unroll
        for (int s = 0; s < 4; ++s) {
            const float xv = xs[s];
            const int t = 4 * it + s;

            // four gate pre-activations via pk-fma; quads consumed in place
            // (pair 2q = hq[q].xy, pair 2q+1 = hq[q].zw); summation order
            // bit-identical to R11.
            f2 accI = f2{fmaf(xv, wxI, bI), 0.f};
            f2 accF = f2{fmaf(xv, wxF, bF), 0.f};
            f2 accG = f2{fmaf(xv, wxG, bG), 0.f};
            f2 accO = f2{fmaf(xv, wxO, bO), 0.f};
#pragma unroll
            for (int q = 0; q < 6; ++q) {
                const f2 hlo = __builtin_shufflevector(hq[q], hq[q], 0, 1);
                const f2 hhi = __builtin_shufflevector(hq[q], hq[q], 2, 3);
                accI = __builtin_elementwise_fma(hlo, wI2[2 * q], accI);
                accF = __builtin_elementwise_fma(hlo, wF2[2 * q], accF);
                accG = __builtin_elementwise_fma(hlo, wG2[2 * q], accG);
                accO = __builtin_elementwise_fma(hlo, wO2[2 * q], accO);
                accI = __builtin_elementwise_fma(hhi, wI2[2 * q + 1], accI);
                accF = __builtin_elementwise_fma(hhi, wF2[2 * q + 1], accF);
                accG = __builtin_elementwise_fma(hhi, wG2[2 * q + 1], accG);
                accO = __builtin_elementwise_fma(hhi, wO2[2 * q + 1], accO);
            }
            accI = __builtin_elementwise_fma(hq6, wI2[12], accI);
            accF = __builtin_elementwise_fma(hq6, wF2[12], accF);
            accG = __builtin_elementwise_fma(hq6, wG2[12], accG);
            accO = __builtin_elementwise_fma(hq6, wO2[12], accO);
            const float aI = accI.x + accI.y;
            const float aF = accF.x + accF.y;
            const float aG = accG.x + accG.y;
            const float aO = accO.x + accO.y;

            const float sI = fast_rcp(1.f + fast_exp2(aI));          // sig(i)
            const float sF = fast_rcp(1.f + fast_exp2(aF));          // sig(f)
            const float sO = fast_rcp(1.f + fast_exp2(aO));          // sig(o)
            const float tG = fmaf(-2.f, fast_rcp(1.f + fast_exp2(aG)), 1.f); // tanh(g)

            c = fmaf(sF, c, sI * tG);
            const float tC = fmaf(-2.f, fast_rcp(1.f + fast_exp2(2.f * LOG2E * c)), 1.f);
            const float hn = sO * tC;

            // ---- ordered publish -> readback (single compile-time fence;
            // same-wave DS ops execute in order on HW) ----
            *hwr = hn;
            hist[cb][t & 31][u] = hn;
            __asm__ __volatile__("" ::: "memory");
            hq[0] = (f4)r4[0]; hq[1] = (f4)r4[1]; hq[2] = (f4)r4[2];
            hq[3] = (f4)r4[3]; hq[4] = (f4)r4[4]; hq[5] = (f4)r4[5];
            hq6 = (f2)r2[0];                     // (h24, 0)

            // batched y: every 32 steps lane u computes y[t0+u] (full 25-sum,
            // hist reads conflict-free by stride-33), all 32 lanes store.
            if ((t & 31) == 31) {
                const float* hrow = &hist[cb][u][0];   // row for t' = t0 + u
                float ys = 0.f;
#pragma unroll
                for (int i = 0; i < HID; ++i)
                    ys = fmaf(hrow[i], wdv[i], ys);
                orow[(t & ~31) + u] = ys + bd;         // 128 B coalesced
            }
        }
        xcur = xnext;
    }
}

extern "C" void kernel_launch(void* const* d_in, const int* in_sizes, int n_in,
                              void* d_out, int out_size, void* d_ws, size_t ws_size,
                              hipStream_t stream) {
    const float* x       = (const float*)d_in[0];
    const float* w_ih    = (const float*)d_in[1];
    const float* w_hh    = (const float*)d_in[2];
    const float* b_ih    = (const float*)d_in[3];
    const float* b_hh    = (const float*)d_in[4];
    const float* w_dense = (const float*)d_in[5];
    const float* b_dense = (const float*)d_in[6];
    float* out = (float*)d_out;

    // 2048 chains, one per 32-lane half-wave: 256 blocks x 256 threads
    // -> 1024 waves = 1 wave/SIMD chip-wide, 4 waves/CU.
    lstm_fused<<<dim3(256), dim3(256), 0, stream>>>(x, w_ih, w_hh, b_ih, b_hh,
                                                    w_dense, b_dense, out);
}